// Round 12
// baseline (329.015 us; speedup 1.0000x reference)
//
#include <hip/hip_runtime.h>
#include <hip/hip_fp16.h>
#include <cstddef>

static constexpr int TPB = 256;
// bucket = 256 consecutive dst nodes (shift 8); NBKT = ceil(N/256) <= 512
static constexpr int MAXBKT = 512;

// ---------------------------------------------------------------- utility
__global__ void k_zero_i(int* __restrict__ p, int n) {
    int stride = gridDim.x * blockDim.x;
    for (int i = blockIdx.x * blockDim.x + threadIdx.x; i < n; i += stride)
        p[i] = 0;
}

// per-block LDS bucket histogram -> few global atomics (256 blocks x NBKT buckets)
__global__ __launch_bounds__(TPB) void k_bucket_hist(const int* __restrict__ dst,
                                                     int* __restrict__ bucket_cnt,
                                                     int E, int nbkt) {
    __shared__ int hist[MAXBKT];
    for (int b = threadIdx.x; b < nbkt; b += TPB) hist[b] = 0;
    __syncthreads();
    int stride = gridDim.x * blockDim.x;
    for (int e = blockIdx.x * blockDim.x + threadIdx.x; e < E; e += stride)
        atomicAdd(&hist[dst[e] >> 8], 1);
    __syncthreads();
    for (int b = threadIdx.x; b < nbkt; b += TPB) {
        int h = hist[b];
        if (h) atomicAdd(&bucket_cnt[b], h);
    }
}

// scan bucket counts -> bucket_lo (start in pairs array) + pair_cur (cursor)
__global__ __launch_bounds__(TPB) void k_bucket_scan(const int* __restrict__ bucket_cnt,
                                                     int nbkt, int* __restrict__ bucket_lo,
                                                     int* __restrict__ pair_cur) {
    __shared__ int bsum[MAXBKT];
    int t = threadIdx.x;
    for (int b = t; b < nbkt; b += TPB) bsum[b] = bucket_cnt[b];
    __syncthreads();
    if (t == 0) {
        int run = 0;
        for (int b = 0; b < nbkt; ++b) { int c = bsum[b]; bsum[b] = run; run += c; }
    }
    __syncthreads();
    for (int b = t; b < nbkt; b += TPB) {
        bucket_lo[b] = bsum[b];
        pair_cur[b]  = bsum[b];
    }
}

// pass 1: partition edges into 256-node buckets; per-(block,bucket) private contiguous
// sub-ranges -> mostly full-line, single-writer HBM writes. pairs entry = (s<<8)|(d&255).
__global__ __launch_bounds__(TPB) void k_partition(const int* __restrict__ src,
                                                   const int* __restrict__ dst,
                                                   int* __restrict__ pair_cur,
                                                   int* __restrict__ pairs, int E, int nbkt) {
    __shared__ int hist[MAXBKT];
    __shared__ int base[MAXBKT];
    const int chunk = (E + gridDim.x - 1) / gridDim.x;
    const int e0 = blockIdx.x * chunk;
    const int e1 = min(e0 + chunk, E);
    for (int b = threadIdx.x; b < nbkt; b += TPB) hist[b] = 0;
    __syncthreads();
    for (int e = e0 + threadIdx.x; e < e1; e += TPB)
        atomicAdd(&hist[dst[e] >> 8], 1);
    __syncthreads();
    for (int b = threadIdx.x; b < nbkt; b += TPB) {
        int h = hist[b];
        base[b] = h ? atomicAdd(&pair_cur[b], h) : 0;
    }
    __syncthreads();
    for (int e = e0 + threadIdx.x; e < e1; e += TPB) {
        int s = src[e], d = dst[e];
        int slot = atomicAdd(&base[d >> 8], 1);
        pairs[slot] = (s << 8) | (d & 255);    // s < 2^17 -> fits
    }
}

// per-bucket node counts from pairs via LDS; coalesced cnt write, zero global atomics
__global__ __launch_bounds__(TPB) void k_count2(const int* __restrict__ bucket_lo,
                                                const int* __restrict__ pair_cur,
                                                const int* __restrict__ pairs,
                                                int* __restrict__ cnt, int N) {
    __shared__ int c[256];
    int b = blockIdx.x;
    c[threadIdx.x] = 0;
    __syncthreads();
    int lo = bucket_lo[b], hi = pair_cur[b];
    for (int k = lo + threadIdx.x; k < hi; k += TPB)
        atomicAdd(&c[pairs[k] & 255], 1);
    __syncthreads();
    int node = (b << 8) + threadIdx.x;
    if (node < N) cnt[node] = c[threadIdx.x];
}

// per-block (1024-elem) sums of PADDED counts (rows padded to 16 entries / 64B)
__global__ __launch_bounds__(TPB) void k_block_sums(const int* __restrict__ cnt,
                                                    int* __restrict__ blockSums, int N) {
    __shared__ int wsum[TPB / 64];
    int base = blockIdx.x * 1024 + threadIdx.x * 4;
    int s = 0;
    #pragma unroll
    for (int j = 0; j < 4; ++j) {
        int i = base + j;
        if (i < N) s += (cnt[i] + 15) & ~15;
    }
    #pragma unroll
    for (int off = 32; off >= 1; off >>= 1) s += __shfl_xor(s, off);
    int lane = threadIdx.x & 63, w = threadIdx.x >> 6;
    if (lane == 0) wsum[w] = s;
    __syncthreads();
    if (threadIdx.x == 0) {
        int t = 0;
        for (int i = 0; i < TPB / 64; ++i) t += wsum[i];
        blockSums[blockIdx.x] = t;
    }
}

// sequential exclusive scan of block sums (nb <= 128: trivial)
__global__ void k_scan_sums(int* __restrict__ blockSums, int nb) {
    if (blockIdx.x == 0 && threadIdx.x == 0) {
        int run = 0;
        for (int b = 0; b < nb; ++b) { int t = blockSums[b]; blockSums[b] = run; run += t; }
    }
}

// local exclusive scan (padded counts) -> 64B-aligned row_start; also dinv
__global__ __launch_bounds__(TPB) void k_scan_local(const int* __restrict__ cnt,
                                                    const int* __restrict__ blockSums,
                                                    int* __restrict__ row_start,
                                                    float* __restrict__ dinv, int N) {
    __shared__ int wsum[TPB / 64];
    int base = blockIdx.x * 1024 + threadIdx.x * 4;
    int c[4], p[4];
    #pragma unroll
    for (int j = 0; j < 4; ++j) {
        int i = base + j;
        c[j] = (i < N) ? cnt[i] : 0;
        p[j] = (c[j] + 15) & ~15;
    }
    int tsum = p[0] + p[1] + p[2] + p[3];
    int lane = threadIdx.x & 63, w = threadIdx.x >> 6;
    int v = tsum;
    #pragma unroll
    for (int off = 1; off < 64; off <<= 1) {
        int u = __shfl_up(v, off);
        if (lane >= off) v += u;
    }
    if (lane == 63) wsum[w] = v;
    __syncthreads();
    int woff = 0;
    for (int i = 0; i < w; ++i) woff += wsum[i];
    int excl = blockSums[blockIdx.x] + woff + (v - tsum);
    #pragma unroll
    for (int j = 0; j < 4; ++j) {
        int i = base + j;
        if (i < N) {
            row_start[i] = excl;
            dinv[i] = rsqrtf(1.0f + (float)c[j]);   // deg = cnt + 1 (self-loop)
            excl += p[j];
        }
    }
}

// pass 2: one block per bucket; LDS cursors (zero global atomics); CSR region per
// bucket (~50KB) is single-writer and L2-resident -> lines fill before eviction.
__global__ __launch_bounds__(TPB) void k_scatter2(const int* __restrict__ bucket_lo,
                                                  const int* __restrict__ pair_cur,
                                                  const int* __restrict__ pairs,
                                                  const int* __restrict__ row_start,
                                                  int* __restrict__ csr, int N) {
    __shared__ int cur[256];
    int b = blockIdx.x;
    int node = (b << 8) + threadIdx.x;
    cur[threadIdx.x] = (node < N) ? row_start[node] : 0;
    __syncthreads();
    int lo = bucket_lo[b], hi = pair_cur[b];
    for (int k = lo + threadIdx.x; k < hi; k += TPB) {
        int p = pairs[k];
        int slot = atomicAdd(&cur[p & 255], 1);
        csr[slot] = p >> 8;
    }
}

// -------- h1h = fp16( dinv * (x @ W1) ), SLICE-MAJOR: h1h[slice][node][16 features]
// slice = f >> 4 (4 slices x 3.2 MB -> each fits a 4MB per-XCD L2)
// quarter-wave per row: lane&15 selects 4 consecutive features, lane>>4 selects row in quad
__global__ __launch_bounds__(TPB) void k_gemm1(const float* __restrict__ x,
                                               const float* __restrict__ W1,
                                               const float* __restrict__ dinv,
                                               __half* __restrict__ h1h, int N) {
    __shared__ float W1s[128 * 64];          // 32 KB
    {
        const float4* W1v = reinterpret_cast<const float4*>(W1);
        float4* W1sv = reinterpret_cast<float4*>(W1s);
        for (int i = threadIdx.x; i < 128 * 64 / 4; i += TPB) W1sv[i] = W1v[i];
    }
    __syncthreads();
    const int lane = threadIdx.x & 63;
    const int wid  = threadIdx.x >> 6;       // 4 waves
    const int q    = lane >> 4;              // row within quad
    const int f4   = (lane & 15) * 4;        // feature base
    const size_t sliceHalfs = (size_t)N * 16;
    const size_t sliceOff = (size_t)(f4 >> 4) * sliceHalfs + (f4 & 15);
    for (int rb = blockIdx.x * 16 + wid * 4; rb < N; rb += gridDim.x * 16) {
        int row = rb + q;
        const float4* xr4 = reinterpret_cast<const float4*>(x + (size_t)row * 128);
        float dn = dinv[row];
        float ax = 0.f, ay = 0.f, az = 0.f, aw = 0.f;
        #pragma unroll 8
        for (int k4 = 0; k4 < 32; ++k4) {
            float4 xv = xr4[k4];             // quarter-uniform broadcast load
            const float4* wrow = reinterpret_cast<const float4*>(&W1s[(k4 * 4) * 64 + f4]);
            float4 w0 = wrow[0];
            float4 w1 = wrow[16];            // next k: +64 floats = +16 float4
            float4 w2 = wrow[32];
            float4 w3 = wrow[48];
            ax = fmaf(xv.x, w0.x, ax); ay = fmaf(xv.x, w0.y, ay);
            az = fmaf(xv.x, w0.z, az); aw = fmaf(xv.x, w0.w, aw);
            ax = fmaf(xv.y, w1.x, ax); ay = fmaf(xv.y, w1.y, ay);
            az = fmaf(xv.y, w1.z, az); aw = fmaf(xv.y, w1.w, aw);
            ax = fmaf(xv.z, w2.x, ax); ay = fmaf(xv.z, w2.y, ay);
            az = fmaf(xv.z, w2.z, az); aw = fmaf(xv.z, w2.w, aw);
            ax = fmaf(xv.w, w3.x, ax); ay = fmaf(xv.w, w3.y, ay);
            az = fmaf(xv.w, w3.z, az); aw = fmaf(xv.w, w3.w, aw);
        }
        __half2 ha = __floats2half2_rn(ax * dn, ay * dn);
        __half2 hb = __floats2half2_rn(az * dn, aw * dn);
        __half2* dst2 = reinterpret_cast<__half2*>(h1h + sliceOff + (size_t)row * 16);
        dst2[0] = ha;
        dst2[1] = hb;
    }
}

// ------------- layer-1 gather, one feature-SLICE per dispatch (L2-resident 3.2MB)
// 4 lanes/edge (8B each = 4 features), 16 edge slots/wave, unroll-2 -> 32 edges in flight.
// v = leaky(dn*sum + b1) for this slice's 16 features; accumulate W2-partial into h2s.
__global__ void k_gather1s(const int* __restrict__ row_start, const int* __restrict__ cnt,
                           const int* __restrict__ csr, const float* __restrict__ dinv,
                           const __half* __restrict__ h1h, const float* __restrict__ b1,
                           const float* __restrict__ W2, float* __restrict__ h2s,
                           int N, int pass) {
    int gtid = blockIdx.x * blockDim.x + threadIdx.x;
    int wid = gtid >> 6, lane = gtid & 63;
    int nwaves = (gridDim.x * blockDim.x) >> 6;
    int slot = lane >> 2, q = lane & 3;
    const uint2* h1v = reinterpret_cast<const uint2*>(h1h) + (size_t)pass * N * 4;
    int fbase = pass * 16 + q * 4;           // this lane's 4 features
    float4 w2r0 = reinterpret_cast<const float4*>(W2)[fbase + 0];
    float4 w2r1 = reinterpret_cast<const float4*>(W2)[fbase + 1];
    float4 w2r2 = reinterpret_cast<const float4*>(W2)[fbase + 2];
    float4 w2r3 = reinterpret_cast<const float4*>(W2)[fbase + 3];
    float4 bl4  = reinterpret_cast<const float4*>(b1)[fbase >> 2];
    for (int node = wid; node < N; node += nwaves) {
        int rc = cnt[node];
        int rs = row_start[node];
        float dn = dinv[node];
        float a0 = 0.f, a1 = 0.f, a2 = 0.f, a3 = 0.f;
        if (slot == 0) {                     // self-loop chunk
            uint2 u = h1v[(size_t)node * 4 + q];
            float2 fa = __half22float2(*reinterpret_cast<__half2*>(&u.x));
            float2 fb = __half22float2(*reinterpret_cast<__half2*>(&u.y));
            a0 = fa.x; a1 = fa.y; a2 = fb.x; a3 = fb.y;
        }
        int k = slot;
        for (; k + 16 < rc; k += 32) {       // 2 independent gathers in flight per lane
            int s0 = csr[rs + k];
            int s1 = csr[rs + k + 16];
            uint2 u0 = h1v[(size_t)s0 * 4 + q];
            uint2 u1 = h1v[(size_t)s1 * 4 + q];
            float2 fa0 = __half22float2(*reinterpret_cast<__half2*>(&u0.x));
            float2 fb0 = __half22float2(*reinterpret_cast<__half2*>(&u0.y));
            float2 fa1 = __half22float2(*reinterpret_cast<__half2*>(&u1.x));
            float2 fb1 = __half22float2(*reinterpret_cast<__half2*>(&u1.y));
            a0 += fa0.x + fa1.x; a1 += fa0.y + fa1.y;
            a2 += fb0.x + fb1.x; a3 += fb0.y + fb1.y;
        }
        if (k < rc) {
            int s0 = csr[rs + k];
            uint2 u = h1v[(size_t)s0 * 4 + q];
            float2 fa = __half22float2(*reinterpret_cast<__half2*>(&u.x));
            float2 fb = __half22float2(*reinterpret_cast<__half2*>(&u.y));
            a0 += fa.x; a1 += fa.y; a2 += fb.x; a3 += fb.y;
        }
        #pragma unroll
        for (int off = 4; off <= 32; off <<= 1) {    // reduce over 16 slots, keep q
            a0 += __shfl_xor(a0, off);
            a1 += __shfl_xor(a1, off);
            a2 += __shfl_xor(a2, off);
            a3 += __shfl_xor(a3, off);
        }
        float px = 0.f, py = 0.f, pz = 0.f, pw = 0.f;
        if (lane < 4) {                      // slot==0 lanes hold the 4-feature totals
            float v0 = fmaf(dn, a0, bl4.x);
            float v1 = fmaf(dn, a1, bl4.y);
            float v2 = fmaf(dn, a2, bl4.z);
            float v3 = fmaf(dn, a3, bl4.w);
            v0 = v0 > 0.f ? v0 : 0.01f * v0;
            v1 = v1 > 0.f ? v1 : 0.01f * v1;
            v2 = v2 > 0.f ? v2 : 0.01f * v2;
            v3 = v3 > 0.f ? v3 : 0.01f * v3;
            px = v0 * w2r0.x + v1 * w2r1.x + v2 * w2r2.x + v3 * w2r3.x;
            py = v0 * w2r0.y + v1 * w2r1.y + v2 * w2r2.y + v3 * w2r3.y;
            pz = v0 * w2r0.z + v1 * w2r1.z + v2 * w2r2.z + v3 * w2r3.z;
            pw = v0 * w2r0.w + v1 * w2r1.w + v2 * w2r2.w + v3 * w2r3.w;
        }
        px += __shfl_xor(px, 1); px += __shfl_xor(px, 2);
        py += __shfl_xor(py, 1); py += __shfl_xor(py, 2);
        pz += __shfl_xor(pz, 1); pz += __shfl_xor(pz, 2);
        pw += __shfl_xor(pw, 1); pw += __shfl_xor(pw, 2);
        if (lane == 0) {
            float4 o = make_float4(px * dn, py * dn, pz * dn, pw * dn);
            if (pass) {
                float4 old = reinterpret_cast<float4*>(h2s)[node];
                o.x += old.x; o.y += old.y; o.z += old.z; o.w += old.w;
            }
            reinterpret_cast<float4*>(h2s)[node] = o;
        }
    }
}

// ------------- layer-2 gather + b2 + softmax -> out [N,4], 16 lanes per node
__global__ void k_gather2(const int* __restrict__ row_start, const int* __restrict__ cnt,
                          const int* __restrict__ csr, const float* __restrict__ dinv,
                          const float* __restrict__ h2s, const float* __restrict__ b2,
                          float* __restrict__ out, int N) {
    int gtid = blockIdx.x * blockDim.x + threadIdx.x;
    int wid = gtid >> 6, lane = gtid & 63;
    int grp = lane >> 4, l = lane & 15;
    int nslots = ((gridDim.x * blockDim.x) >> 6) * 4;
    float b0 = b2[0], b1v = b2[1], b2v = b2[2], b3 = b2[3];
    for (int node = wid * 4 + grp; node < N; node += nslots) {
        int rc = cnt[node];
        int rs = row_start[node];
        float a0 = 0.f, a1 = 0.f, a2 = 0.f, a3 = 0.f;
        for (int k = l; k < rc; k += 16) {
            int s = csr[rs + k];
            float4 hv = reinterpret_cast<const float4*>(h2s)[s];
            a0 += hv.x; a1 += hv.y; a2 += hv.z; a3 += hv.w;
        }
        #pragma unroll
        for (int off = 1; off <= 8; off <<= 1) {
            a0 += __shfl_xor(a0, off);
            a1 += __shfl_xor(a1, off);
            a2 += __shfl_xor(a2, off);
            a3 += __shfl_xor(a3, off);
        }
        if (l == 0) {
            float dn = dinv[node];
            float4 hs = reinterpret_cast<const float4*>(h2s)[node];  // self-loop
            float v0 = fmaf(dn, a0 + hs.x, b0);
            float v1 = fmaf(dn, a1 + hs.y, b1v);
            float v2 = fmaf(dn, a2 + hs.z, b2v);
            float v3 = fmaf(dn, a3 + hs.w, b3);
            float m = fmaxf(fmaxf(v0, v1), fmaxf(v2, v3));
            float e0 = __expf(v0 - m), e1 = __expf(v1 - m);
            float e2 = __expf(v2 - m), e3 = __expf(v3 - m);
            float s = 1.0f / (e0 + e1 + e2 + e3);
            reinterpret_cast<float4*>(out)[node] = make_float4(e0 * s, e1 * s, e2 * s, e3 * s);
        }
    }
}

// ----------------------------------------------------------------
extern "C" void kernel_launch(void* const* d_in, const int* in_sizes, int n_in,
                              void* d_out, int out_size, void* d_ws, size_t ws_size,
                              hipStream_t stream) {
    const float* x  = (const float*)d_in[0];
    const float* W1 = (const float*)d_in[1];
    const float* b1 = (const float*)d_in[2];
    const float* W2 = (const float*)d_in[3];
    const float* b2 = (const float*)d_in[4];
    const int*   ei = (const int*)d_in[5];

    const int N = in_sizes[0] / 128;
    const int E = in_sizes[5] / 2;
    const int* src = ei;
    const int* dst = ei + E;

    const int NB   = (N + 1023) / 1024;      // scan blocks (98 for N=100000)
    const int NBKT = (N + 255) / 256;        // 391 buckets for N=100000

    char* w = (char*)d_ws;
    int*    cnt        = (int*)w;            w += (size_t)N * 4;
    int*    row_start  = (int*)w;            w += (size_t)N * 4;
    int*    blockSums  = (int*)w;            w += 128 * 4;
    int*    bucket_cnt = (int*)w;            w += MAXBKT * 4;
    int*    bucket_lo  = (int*)w;            w += MAXBKT * 4;
    int*    pair_cur   = (int*)w;            w += MAXBKT * 4;
    float*  dinv       = (float*)w;          w += (size_t)N * 4;
    __half* h1h        = (__half*)w;         w += (size_t)N * 64 * 2;  // 12.8 MB slice-major
    float*  h2s        = (float*)w;          w += (size_t)N * 4 * 4;
    int*    csr        = (int*)w;            // (E + 15N) * 4 bytes worst case
    int*    pairs      = (int*)h1h;          // alias (12.8 MB): consumed before gemm1 writes

    k_zero_i<<<1, TPB, 0, stream>>>(bucket_cnt, NBKT);
    k_bucket_hist<<<256, TPB, 0, stream>>>(dst, bucket_cnt, E, NBKT);
    k_bucket_scan<<<1, TPB, 0, stream>>>(bucket_cnt, NBKT, bucket_lo, pair_cur);
    k_partition<<<256, TPB, 0, stream>>>(src, dst, pair_cur, pairs, E, NBKT);
    k_count2<<<NBKT, TPB, 0, stream>>>(bucket_lo, pair_cur, pairs, cnt, N);
    k_block_sums<<<NB, TPB, 0, stream>>>(cnt, blockSums, N);
    k_scan_sums<<<1, 64, 0, stream>>>(blockSums, NB);
    k_scan_local<<<NB, TPB, 0, stream>>>(cnt, blockSums, row_start, dinv, N);
    k_scatter2<<<NBKT, TPB, 0, stream>>>(bucket_lo, pair_cur, pairs, row_start, csr, N);
    k_gemm1<<<2048, TPB, 0, stream>>>(x, W1, dinv, h1h, N);   // after pairs consumed
    for (int p = 0; p < 4; ++p)
        k_gather1s<<<2048, TPB, 0, stream>>>(row_start, cnt, csr, dinv, h1h, b1, W2, h2s, N, p);
    k_gather2<<<2048, TPB, 0, stream>>>(row_start, cnt, csr, dinv, h2s, b2, (float*)d_out, N);
}

// Round 13
// 214.430 us; speedup vs baseline: 1.5344x; 1.5344x over previous
//
#include <hip/hip_runtime.h>
#include <hip/hip_fp16.h>
#include <cstddef>

static constexpr int TPB = 256;
static constexpr int TPB_BIG = 1024;         // for grid-starved build kernels
// bucket = 256 consecutive dst nodes (shift 8); NBKT = ceil(N/256) <= 512
static constexpr int MAXBKT = 512;

// ---------------------------------------------------------------- utility
__global__ void k_zero_i(int* __restrict__ p, int n) {
    int stride = gridDim.x * blockDim.x;
    for (int i = blockIdx.x * blockDim.x + threadIdx.x; i < n; i += stride)
        p[i] = 0;
}

// per-block LDS bucket histogram -> few global atomics (256 blocks x NBKT buckets)
__global__ __launch_bounds__(TPB_BIG) void k_bucket_hist(const int* __restrict__ dst,
                                                         int* __restrict__ bucket_cnt,
                                                         int E, int nbkt) {
    __shared__ int hist[MAXBKT];
    for (int b = threadIdx.x; b < nbkt; b += TPB_BIG) hist[b] = 0;
    __syncthreads();
    int stride = gridDim.x * blockDim.x;
    for (int e = blockIdx.x * blockDim.x + threadIdx.x; e < E; e += stride)
        atomicAdd(&hist[dst[e] >> 8], 1);
    __syncthreads();
    for (int b = threadIdx.x; b < nbkt; b += TPB_BIG) {
        int h = hist[b];
        if (h) atomicAdd(&bucket_cnt[b], h);
    }
}

// scan bucket counts -> bucket_lo (start in pairs array) + pair_cur (cursor)
__global__ __launch_bounds__(TPB) void k_bucket_scan(const int* __restrict__ bucket_cnt,
                                                     int nbkt, int* __restrict__ bucket_lo,
                                                     int* __restrict__ pair_cur) {
    __shared__ int bsum[MAXBKT];
    int t = threadIdx.x;
    for (int b = t; b < nbkt; b += TPB) bsum[b] = bucket_cnt[b];
    __syncthreads();
    if (t == 0) {
        int run = 0;
        for (int b = 0; b < nbkt; ++b) { int c = bsum[b]; bsum[b] = run; run += c; }
    }
    __syncthreads();
    for (int b = t; b < nbkt; b += TPB) {
        bucket_lo[b] = bsum[b];
        pair_cur[b]  = bsum[b];
    }
}

// pass 1: partition edges into 256-node buckets; per-(block,bucket) private contiguous
// sub-ranges -> mostly full-line, single-writer HBM writes. pairs entry = (s<<8)|(d&255).
// TPB=1024, grid=256: 16 waves/CU (was 4) -> latency-bound loops get 4x parallelism
// while keeping 256 blocks (same number of write runs, no extra write amplification).
__global__ __launch_bounds__(TPB_BIG) void k_partition(const int* __restrict__ src,
                                                       const int* __restrict__ dst,
                                                       int* __restrict__ pair_cur,
                                                       int* __restrict__ pairs, int E, int nbkt) {
    __shared__ int hist[MAXBKT];
    __shared__ int base[MAXBKT];
    const int chunk = (E + gridDim.x - 1) / gridDim.x;
    const int e0 = blockIdx.x * chunk;
    const int e1 = min(e0 + chunk, E);
    for (int b = threadIdx.x; b < nbkt; b += TPB_BIG) hist[b] = 0;
    __syncthreads();
    for (int e = e0 + threadIdx.x; e < e1; e += TPB_BIG)
        atomicAdd(&hist[dst[e] >> 8], 1);
    __syncthreads();
    for (int b = threadIdx.x; b < nbkt; b += TPB_BIG) {
        int h = hist[b];
        base[b] = h ? atomicAdd(&pair_cur[b], h) : 0;
    }
    __syncthreads();
    for (int e = e0 + threadIdx.x; e < e1; e += TPB_BIG) {
        int s = src[e], d = dst[e];
        int slot = atomicAdd(&base[d >> 8], 1);
        pairs[slot] = (s << 8) | (d & 255);    // s < 2^17 -> fits
    }
}

// per-bucket node counts from pairs via LDS; coalesced cnt write, zero global atomics
__global__ __launch_bounds__(512) void k_count2(const int* __restrict__ bucket_lo,
                                                const int* __restrict__ pair_cur,
                                                const int* __restrict__ pairs,
                                                int* __restrict__ cnt, int N) {
    __shared__ int c[256];
    int b = blockIdx.x;
    if (threadIdx.x < 256) c[threadIdx.x] = 0;
    __syncthreads();
    int lo = bucket_lo[b], hi = pair_cur[b];
    for (int k = lo + threadIdx.x; k < hi; k += 512)
        atomicAdd(&c[pairs[k] & 255], 1);
    __syncthreads();
    if (threadIdx.x < 256) {
        int node = (b << 8) + threadIdx.x;
        if (node < N) cnt[node] = c[threadIdx.x];
    }
}

// per-block (1024-elem) sums of PADDED counts (rows padded to 16 entries / 64B)
__global__ __launch_bounds__(TPB) void k_block_sums(const int* __restrict__ cnt,
                                                    int* __restrict__ blockSums, int N) {
    __shared__ int wsum[TPB / 64];
    int base = blockIdx.x * 1024 + threadIdx.x * 4;
    int s = 0;
    #pragma unroll
    for (int j = 0; j < 4; ++j) {
        int i = base + j;
        if (i < N) s += (cnt[i] + 15) & ~15;
    }
    #pragma unroll
    for (int off = 32; off >= 1; off >>= 1) s += __shfl_xor(s, off);
    int lane = threadIdx.x & 63, w = threadIdx.x >> 6;
    if (lane == 0) wsum[w] = s;
    __syncthreads();
    if (threadIdx.x == 0) {
        int t = 0;
        for (int i = 0; i < TPB / 64; ++i) t += wsum[i];
        blockSums[blockIdx.x] = t;
    }
}

// sequential exclusive scan of block sums (nb <= 128: trivial)
__global__ void k_scan_sums(int* __restrict__ blockSums, int nb) {
    if (blockIdx.x == 0 && threadIdx.x == 0) {
        int run = 0;
        for (int b = 0; b < nb; ++b) { int t = blockSums[b]; blockSums[b] = run; run += t; }
    }
}

// local exclusive scan (padded counts) -> 64B-aligned row_start; also dinv
__global__ __launch_bounds__(TPB) void k_scan_local(const int* __restrict__ cnt,
                                                    const int* __restrict__ blockSums,
                                                    int* __restrict__ row_start,
                                                    float* __restrict__ dinv, int N) {
    __shared__ int wsum[TPB / 64];
    int base = blockIdx.x * 1024 + threadIdx.x * 4;
    int c[4], p[4];
    #pragma unroll
    for (int j = 0; j < 4; ++j) {
        int i = base + j;
        c[j] = (i < N) ? cnt[i] : 0;
        p[j] = (c[j] + 15) & ~15;
    }
    int tsum = p[0] + p[1] + p[2] + p[3];
    int lane = threadIdx.x & 63, w = threadIdx.x >> 6;
    int v = tsum;
    #pragma unroll
    for (int off = 1; off < 64; off <<= 1) {
        int u = __shfl_up(v, off);
        if (lane >= off) v += u;
    }
    if (lane == 63) wsum[w] = v;
    __syncthreads();
    int woff = 0;
    for (int i = 0; i < w; ++i) woff += wsum[i];
    int excl = blockSums[blockIdx.x] + woff + (v - tsum);
    #pragma unroll
    for (int j = 0; j < 4; ++j) {
        int i = base + j;
        if (i < N) {
            row_start[i] = excl;
            dinv[i] = rsqrtf(1.0f + (float)c[j]);   // deg = cnt + 1 (self-loop)
            excl += p[j];
        }
    }
}

// pass 2: one block per bucket; LDS cursors (zero global atomics); CSR region per
// bucket (~50KB) is single-writer and L2-resident -> lines fill before eviction.
__global__ __launch_bounds__(512) void k_scatter2(const int* __restrict__ bucket_lo,
                                                  const int* __restrict__ pair_cur,
                                                  const int* __restrict__ pairs,
                                                  const int* __restrict__ row_start,
                                                  int* __restrict__ csr, int N) {
    __shared__ int cur[256];
    int b = blockIdx.x;
    if (threadIdx.x < 256) {
        int node = (b << 8) + threadIdx.x;
        cur[threadIdx.x] = (node < N) ? row_start[node] : 0;
    }
    __syncthreads();
    int lo = bucket_lo[b], hi = pair_cur[b];
    for (int k = lo + threadIdx.x; k < hi; k += 512) {
        int p = pairs[k];
        int slot = atomicAdd(&cur[p & 255], 1);
        csr[slot] = p >> 8;
    }
}

// -------------------- h1h = fp16( dinv * (x @ W1) )   [N,128]x[128,64], row-scaled
// quarter-wave per row: lane&15 selects 4 consecutive features, lane>>4 selects row in quad
__global__ __launch_bounds__(TPB) void k_gemm1(const float* __restrict__ x,
                                               const float* __restrict__ W1,
                                               const float* __restrict__ dinv,
                                               __half* __restrict__ h1h, int N) {
    __shared__ float W1s[128 * 64];          // 32 KB
    {
        const float4* W1v = reinterpret_cast<const float4*>(W1);
        float4* W1sv = reinterpret_cast<float4*>(W1s);
        for (int i = threadIdx.x; i < 128 * 64 / 4; i += TPB) W1sv[i] = W1v[i];
    }
    __syncthreads();
    const int lane = threadIdx.x & 63;
    const int wid  = threadIdx.x >> 6;       // 4 waves
    const int q    = lane >> 4;              // row within quad
    const int f4   = (lane & 15) * 4;        // feature base
    for (int rb = blockIdx.x * 16 + wid * 4; rb < N; rb += gridDim.x * 16) {
        int row = rb + q;
        const float4* xr4 = reinterpret_cast<const float4*>(x + (size_t)row * 128);
        float dn = dinv[row];
        float ax = 0.f, ay = 0.f, az = 0.f, aw = 0.f;
        #pragma unroll 8
        for (int k4 = 0; k4 < 32; ++k4) {
            float4 xv = xr4[k4];             // quarter-uniform broadcast load
            const float4* wrow = reinterpret_cast<const float4*>(&W1s[(k4 * 4) * 64 + f4]);
            float4 w0 = wrow[0];
            float4 w1 = wrow[16];            // next k: +64 floats = +16 float4
            float4 w2 = wrow[32];
            float4 w3 = wrow[48];
            ax = fmaf(xv.x, w0.x, ax); ay = fmaf(xv.x, w0.y, ay);
            az = fmaf(xv.x, w0.z, az); aw = fmaf(xv.x, w0.w, aw);
            ax = fmaf(xv.y, w1.x, ax); ay = fmaf(xv.y, w1.y, ay);
            az = fmaf(xv.y, w1.z, az); aw = fmaf(xv.y, w1.w, aw);
            ax = fmaf(xv.z, w2.x, ax); ay = fmaf(xv.z, w2.y, ay);
            az = fmaf(xv.z, w2.z, az); aw = fmaf(xv.z, w2.w, aw);
            ax = fmaf(xv.w, w3.x, ax); ay = fmaf(xv.w, w3.y, ay);
            az = fmaf(xv.w, w3.z, az); aw = fmaf(xv.w, w3.w, aw);
        }
        __half2 ha = __floats2half2_rn(ax * dn, ay * dn);
        __half2 hb = __floats2half2_rn(az * dn, aw * dn);
        __half2* dst2 = reinterpret_cast<__half2*>(h1h + (size_t)row * 64 + f4);
        dst2[0] = ha;
        dst2[1] = hb;
    }
}

// ------------- layer-1 gather (fp16 rows, 2 features/lane, 8 edges in flight/wave)
//               + bias + leaky_relu + @W2 -> h2s [N,4], wave per node
__global__ void k_gather1(const int* __restrict__ row_start, const int* __restrict__ cnt,
                          const int* __restrict__ csr, const float* __restrict__ dinv,
                          const __half* __restrict__ h1h, const float* __restrict__ b1,
                          const float* __restrict__ W2, float* __restrict__ h2s, int N) {
    int gtid = blockIdx.x * blockDim.x + threadIdx.x;
    int wid = gtid >> 6, lane = gtid & 63;
    int nwaves = (gridDim.x * blockDim.x) >> 6;
    int eh = lane >> 5;                      // which half-wave
    int f2 = lane & 31;                      // feature pair: features 2f2, 2f2+1
    float4 w2a = reinterpret_cast<const float4*>(W2)[2 * f2];      // W2[2f2][0..3]
    float4 w2b = reinterpret_cast<const float4*>(W2)[2 * f2 + 1];  // W2[2f2+1][0..3]
    float2 bl = reinterpret_cast<const float2*>(b1)[f2];
    const __half2* h1v = reinterpret_cast<const __half2*>(h1h);
    for (int node = wid; node < N; node += nwaves) {
        int rc = cnt[node];
        int rs = row_start[node];            // 16-aligned
        float dn = dinv[node];
        float ax = 0.f, ay = 0.f;
        if (eh == 0) {                       // self-loop term once
            float2 f = __half22float2(h1v[(size_t)node * 32 + f2]);
            ax = f.x; ay = f.y;
        }
        // main: chunks of 8 edges; each half-wave takes 4 via one int4 broadcast,
        // issues 4 independent row-gathers -> 8 rows in flight per wave
        int m = 0;
        for (; m + 8 <= rc; m += 8) {
            int4 cc = *reinterpret_cast<const int4*>(csr + rs + m + eh * 4);
            float2 f0 = __half22float2(h1v[(size_t)cc.x * 32 + f2]);
            float2 f1 = __half22float2(h1v[(size_t)cc.y * 32 + f2]);
            float2 f2v = __half22float2(h1v[(size_t)cc.z * 32 + f2]);
            float2 f3 = __half22float2(h1v[(size_t)cc.w * 32 + f2]);
            ax += (f0.x + f1.x) + (f2v.x + f3.x);
            ay += (f0.y + f1.y) + (f2v.y + f3.y);
        }
        for (int k = m + eh; k < rc; k += 2) {   // tail (<8 edges)
            int s = csr[rs + k];
            float2 f = __half22float2(h1v[(size_t)s * 32 + f2]);
            ax += f.x; ay += f.y;
        }
        ax += __shfl_xor(ax, 32);            // combine the two half-waves
        ay += __shfl_xor(ay, 32);
        float v0 = fmaf(dn, ax, bl.x);
        float v1 = fmaf(dn, ay, bl.y);
        v0 = v0 > 0.f ? v0 : 0.01f * v0;     // leaky_relu(0.01)
        v1 = v1 > 0.f ? v1 : 0.01f * v1;
        float px = v0 * w2a.x + v1 * w2b.x;
        float py = v0 * w2a.y + v1 * w2b.y;
        float pz = v0 * w2a.z + v1 * w2b.z;
        float pw = v0 * w2a.w + v1 * w2b.w;
        #pragma unroll
        for (int off = 16; off >= 1; off >>= 1) {
            px += __shfl_xor(px, off);
            py += __shfl_xor(py, off);
            pz += __shfl_xor(pz, off);
            pw += __shfl_xor(pw, off);
        }
        if (lane == 0)
            reinterpret_cast<float4*>(h2s)[node] =
                make_float4(px * dn, py * dn, pz * dn, pw * dn);   // pre-scale by dinv
    }
}

// ------------- layer-2 gather + b2 + softmax -> out [N,4], 16 lanes per node
__global__ void k_gather2(const int* __restrict__ row_start, const int* __restrict__ cnt,
                          const int* __restrict__ csr, const float* __restrict__ dinv,
                          const float* __restrict__ h2s, const float* __restrict__ b2,
                          float* __restrict__ out, int N) {
    int gtid = blockIdx.x * blockDim.x + threadIdx.x;
    int wid = gtid >> 6, lane = gtid & 63;
    int grp = lane >> 4, l = lane & 15;
    int nslots = ((gridDim.x * blockDim.x) >> 6) * 4;
    float b0 = b2[0], b1v = b2[1], b2v = b2[2], b3 = b2[3];
    for (int node = wid * 4 + grp; node < N; node += nslots) {
        int rc = cnt[node];
        int rs = row_start[node];
        float a0 = 0.f, a1 = 0.f, a2 = 0.f, a3 = 0.f;
        for (int k = l; k < rc; k += 16) {
            int s = csr[rs + k];
            float4 hv = reinterpret_cast<const float4*>(h2s)[s];
            a0 += hv.x; a1 += hv.y; a2 += hv.z; a3 += hv.w;
        }
        #pragma unroll
        for (int off = 1; off <= 8; off <<= 1) {
            a0 += __shfl_xor(a0, off);
            a1 += __shfl_xor(a1, off);
            a2 += __shfl_xor(a2, off);
            a3 += __shfl_xor(a3, off);
        }
        if (l == 0) {
            float dn = dinv[node];
            float4 hs = reinterpret_cast<const float4*>(h2s)[node];  // self-loop
            float v0 = fmaf(dn, a0 + hs.x, b0);
            float v1 = fmaf(dn, a1 + hs.y, b1v);
            float v2 = fmaf(dn, a2 + hs.z, b2v);
            float v3 = fmaf(dn, a3 + hs.w, b3);
            float m = fmaxf(fmaxf(v0, v1), fmaxf(v2, v3));
            float e0 = __expf(v0 - m), e1 = __expf(v1 - m);
            float e2 = __expf(v2 - m), e3 = __expf(v3 - m);
            float s = 1.0f / (e0 + e1 + e2 + e3);
            reinterpret_cast<float4*>(out)[node] = make_float4(e0 * s, e1 * s, e2 * s, e3 * s);
        }
    }
}

// ----------------------------------------------------------------
extern "C" void kernel_launch(void* const* d_in, const int* in_sizes, int n_in,
                              void* d_out, int out_size, void* d_ws, size_t ws_size,
                              hipStream_t stream) {
    const float* x  = (const float*)d_in[0];
    const float* W1 = (const float*)d_in[1];
    const float* b1 = (const float*)d_in[2];
    const float* W2 = (const float*)d_in[3];
    const float* b2 = (const float*)d_in[4];
    const int*   ei = (const int*)d_in[5];

    const int N = in_sizes[0] / 128;
    const int E = in_sizes[5] / 2;
    const int* src = ei;
    const int* dst = ei + E;

    const int NB   = (N + 1023) / 1024;      // scan blocks (98 for N=100000)
    const int NBKT = (N + 255) / 256;        // 391 buckets for N=100000

    char* w = (char*)d_ws;
    int*    cnt        = (int*)w;            w += (size_t)N * 4;
    int*    row_start  = (int*)w;            w += (size_t)N * 4;
    int*    blockSums  = (int*)w;            w += 128 * 4;
    int*    bucket_cnt = (int*)w;            w += MAXBKT * 4;
    int*    bucket_lo  = (int*)w;            w += MAXBKT * 4;
    int*    pair_cur   = (int*)w;            w += MAXBKT * 4;
    float*  dinv       = (float*)w;          w += (size_t)N * 4;
    __half* h1h        = (__half*)w;         w += (size_t)N * 64 * 4;  // fp16 in fp32-sized slot
    float*  h2s        = (float*)w;          w += (size_t)N * 4 * 4;
    int*    csr        = (int*)w;            // (E + 15N) * 4 bytes worst case
    int*    pairs      = (int*)h1h;          // alias: consumed before k_gemm1 writes h1h

    k_zero_i<<<1, TPB, 0, stream>>>(bucket_cnt, NBKT);
    k_bucket_hist<<<256, TPB_BIG, 0, stream>>>(dst, bucket_cnt, E, NBKT);
    k_bucket_scan<<<1, TPB, 0, stream>>>(bucket_cnt, NBKT, bucket_lo, pair_cur);
    k_partition<<<256, TPB_BIG, 0, stream>>>(src, dst, pair_cur, pairs, E, NBKT);
    k_count2<<<NBKT, 512, 0, stream>>>(bucket_lo, pair_cur, pairs, cnt, N);
    k_block_sums<<<NB, TPB, 0, stream>>>(cnt, blockSums, N);
    k_scan_sums<<<1, 64, 0, stream>>>(blockSums, NB);
    k_scan_local<<<NB, TPB, 0, stream>>>(cnt, blockSums, row_start, dinv, N);
    k_scatter2<<<NBKT, 512, 0, stream>>>(bucket_lo, pair_cur, pairs, row_start, csr, N);
    k_gemm1<<<2048, TPB, 0, stream>>>(x, W1, dinv, h1h, N);   // after pairs consumed
    k_gather1<<<2048, TPB, 0, stream>>>(row_start, cnt, csr, dinv, h1h, b1, W2, h2s, N);
    k_gather2<<<2048, TPB, 0, stream>>>(row_start, cnt, csr, dinv, h2s, b2, (float*)d_out, N);
}